// Round 7
// baseline (393.688 us; speedup 1.0000x reference)
//
#include <hip/hip_runtime.h>
#include <hip/hip_bf16.h>

constexpr int Bn = 16, Cn = 24, Sn = 128, En = 256, Hn = 8, Pn = 32;
constexpr size_t NBUF = (size_t)Bn * Cn * Sn * En;   // 12,582,912 elems
constexpr size_t WSLOT = (size_t)Cn * 256 * 256;     // 1,572,864

typedef __bf16 bf16_t;
typedef bf16_t bf16x8 __attribute__((ext_vector_type(8)));
typedef bf16_t bf16x4 __attribute__((ext_vector_type(4)));
typedef float f32x4 __attribute__((ext_vector_type(4)));

// global -> LDS direct 16B copy (dest = wave-uniform base + lane*16)
__device__ __forceinline__ void gl2lds16(const bf16_t* g, bf16_t* l) {
    typedef const __attribute__((address_space(1))) unsigned int* gp_t;
    typedef __attribute__((address_space(3))) unsigned int* lp_t;
    __builtin_amdgcn_global_load_lds((gp_t)(unsigned long long)g,
                                     (lp_t)(unsigned int)(unsigned long long)l,
                                     16, 0, 0);
}

// ---------------------------------------------------------------------------
// x fp32 -> bf16
// ---------------------------------------------------------------------------
__global__ __launch_bounds__(256) void conv_x_k(const float* __restrict__ x,
                                                bf16_t* __restrict__ xb) {
    const size_t i = ((size_t)blockIdx.x * 256 + threadIdx.x) * 4;
    const float4 v = *(const float4*)(x + i);
    bf16x4 o = {(bf16_t)v.x, (bf16_t)v.y, (bf16_t)v.z, (bf16_t)v.w};
    *(bf16x4*)(xb + i) = o;
}

// ---------------------------------------------------------------------------
// Wq_s copy-convert (source already e-contiguous): [h,c,p,e] -> [c][n=h*32+p][e]
// ---------------------------------------------------------------------------
__global__ __launch_bounds__(256) void conv_w_copy_k(const float* __restrict__ W,
                                                     bf16_t* __restrict__ out) {
    const int row = blockIdx.x * 4 + (threadIdx.x >> 6);   // c*256+n
    const int lane = threadIdx.x & 63;
    const int n = row & 255, c = row >> 8;
    const float* src = W + (size_t)c * (Pn * En) + (size_t)(n >> 5) * (Cn * Pn * En) +
                       (size_t)(n & 31) * En + lane * 4;
    const float4 v = *(const float4*)src;
    bf16x4 o = {(bf16_t)v.x, (bf16_t)v.y, (bf16_t)v.z, (bf16_t)v.w};
    *(bf16x4*)(out + (size_t)row * 256 + lane * 4) = o;
}

// ---------------------------------------------------------------------------
// Transpose-convert for e-strided weights -> canonical [slot][c][n][e].
// ---------------------------------------------------------------------------
struct TDesc { const float* W; int Sc, Snh, Se; };

__global__ __launch_bounds__(256) void conv_w_tr_k(
    TDesc d0, TDesc d1, TDesc d2, TDesc d3, TDesc d4,
    bf16_t* __restrict__ out)
{
    TDesc d;
    switch (blockIdx.z) {
        case 0: d = d0; break; case 1: d = d1; break; case 2: d = d2; break;
        case 3: d = d3; break; default: d = d4; break;
    }
    const int g = blockIdx.x & 7, et = blockIdx.x >> 3;
    const int c = blockIdx.y;

    __shared__ float tile[32][65];

    const int t = threadIdx.x;
    const float* base = d.W + (size_t)c * d.Sc + (size_t)g * d.Snh;

#pragma unroll
    for (int pass = 0; pass < 2; ++pass) {
        const int e_local = pass * 32 + (t >> 3);
        const int j4 = (t & 7) * 4;
        const float4 v = *(const float4*)(base + (size_t)(et * 64 + e_local) * d.Se + j4);
        tile[j4 + 0][e_local] = v.x;
        tile[j4 + 1][e_local] = v.y;
        tile[j4 + 2][e_local] = v.z;
        tile[j4 + 3][e_local] = v.w;
    }
    __syncthreads();

    const int j = t >> 3, e8 = (t & 7) * 8;
    bf16x8 o;
#pragma unroll
    for (int k = 0; k < 8; ++k) o[k] = (bf16_t)tile[j][e8 + k];
    *(bf16x8*)(out + (size_t)blockIdx.z * WSLOT +
               ((size_t)c * 256 + g * 32 + j) * 256 + et * 64 + e8) = o;
}

// small shared spatial k/v weights (merged pair, 64 KB each)
__global__ __launch_bounds__(256) void conv_w_k2(const float* __restrict__ Wk,
                                                 const float* __restrict__ Wv,
                                                 bf16_t* __restrict__ Ok,
                                                 bf16_t* __restrict__ Ov) {
    const float* W = blockIdx.y ? Wv : Wk;
    bf16_t* o = blockIdx.y ? Ov : Ok;
    const int n = blockIdx.x, e = threadIdx.x;
    o[(size_t)n * 256 + e] =
        (bf16_t)W[(size_t)(n >> 5) * (En * Pn) + (n & 31) + (size_t)e * Pn];
}

// ---------------------------------------------------------------------------
// bf16 MFMA GEMM (QKV projections), 3 fused projections sharing A.
// 3-buf counted-vmcnt pipeline + source-side XOR swizzle (see R4 notes).
// trans=0: output n-inner; trans=1: output m-inner.
// ---------------------------------------------------------------------------
struct GDesc { const bf16_t* W; bf16_t* O; int Aoff, Wc, Ob, Oc, Os, Onh, Onp, trans; };

template <int NP>
__global__ __launch_bounds__(256) void gemm_mfma(
    const bf16_t* __restrict__ A, int Ab, int Ac, int As,
    GDesc g0, GDesc g1, GDesc g2)
{
    const int b = blockIdx.x, c = blockIdx.z;
    const int proj = (NP == 1) ? 0 : ((int)blockIdx.y >> 1);
    const int nt = (NP == 1) ? (int)blockIdx.y : ((int)blockIdx.y & 1);
    GDesc g = (proj == 0) ? g0 : (proj == 1) ? g1 : g2;

    __shared__ bf16_t smem[3][2][128 * 32];   // 48 KB
    bf16_t* Cs = &smem[0][0][0];              // epilogue staging (aliased)

    const int tid = threadIdx.x, wv = tid >> 6, ln = tid & 63;
    const int wm = (wv >> 1) * 64, wn = (wv & 1) * 64;
    const int lr = ln & 15, hi = ln >> 4;

    const bf16_t* Abase = A + g.Aoff + (size_t)b * Ab + (size_t)c * Ac;
    const bf16_t* Bbase = g.W + (size_t)c * g.Wc + (size_t)(nt * 128) * 256;

    auto stage = [&](int buf, int kt) {
        const int k0 = kt * 32;
#pragma unroll
        for (int it = 0; it < 2; ++it) {
            const int cb = it * 256 + wv * 64;
            const int mc = cb + ln;
            const int row = mc >> 2;
            const int kc = (((mc & 3) ^ ((row >> 1) & 3)) * 8);
            gl2lds16(Abase + (size_t)row * As + k0 + kc, &smem[buf][0][cb * 8]);
            gl2lds16(Bbase + (size_t)row * 256 + k0 + kc, &smem[buf][1][cb * 8]);
        }
    };

    f32x4 acc[4][4] = {};

    stage(0, 0);
    stage(1, 1);

#pragma unroll
    for (int kt = 0; kt < 8; ++kt) {
        if (kt < 6) stage((kt + 2) % 3, kt + 2);
        if (kt < 6)       asm volatile("s_waitcnt vmcnt(8)" ::: "memory");
        else if (kt == 6) asm volatile("s_waitcnt vmcnt(4)" ::: "memory");
        else              asm volatile("s_waitcnt vmcnt(0)" ::: "memory");
        __builtin_amdgcn_s_barrier();
        __builtin_amdgcn_sched_barrier(0);

        const int cur = kt % 3;
        bf16x8 af[4], bfr[4];
#pragma unroll
        for (int i = 0; i < 4; ++i) {
            const int r = wm + i * 16 + lr;
            af[i] = *(const bf16x8*)&smem[cur][0][r * 32 + ((hi ^ ((r >> 1) & 3)) * 8)];
        }
#pragma unroll
        for (int j = 0; j < 4; ++j) {
            const int r = wn + j * 16 + lr;
            bfr[j] = *(const bf16x8*)&smem[cur][1][r * 32 + ((hi ^ ((r >> 1) & 3)) * 8)];
        }
        __builtin_amdgcn_s_setprio(1);
#pragma unroll
        for (int i = 0; i < 4; ++i)
#pragma unroll
            for (int j = 0; j < 4; ++j)
                acc[i][j] = __builtin_amdgcn_mfma_f32_16x16x32_bf16(af[i], bfr[j], acc[i][j], 0, 0, 0);
        __builtin_amdgcn_s_setprio(0);

        __builtin_amdgcn_sched_barrier(0);
        __builtin_amdgcn_s_barrier();
    }

#pragma unroll
    for (int pass = 0; pass < 2; ++pass) {
        if (!g.trans) {
            if (wm == pass * 64) {
#pragma unroll
                for (int i = 0; i < 4; ++i)
#pragma unroll
                    for (int j = 0; j < 4; ++j)
#pragma unroll
                        for (int r = 0; r < 4; ++r)
                            Cs[(i * 16 + hi * 4 + r) * 136 + wn + j * 16 + lr] =
                                (bf16_t)acc[i][j][r];
            }
            __syncthreads();
#pragma unroll
            for (int it = 0; it < 2; ++it) {
                const int lrow = it * 32 + (tid >> 3);
                const int n0 = (tid & 7) * 16;
                bf16x8 v0 = *(const bf16x8*)&Cs[lrow * 136 + n0];
                bf16x8 v1 = *(const bf16x8*)&Cs[lrow * 136 + n0 + 8];
                const int m = pass * 64 + lrow;
                const int n = nt * 128 + n0;
                bf16_t* dst = g.O + (size_t)b * g.Ob + (size_t)c * g.Oc +
                              (size_t)m * g.Os + (size_t)(n >> 5) * g.Onh + (n & 31);
                *(bf16x8*)dst = v0;
                *(bf16x8*)(dst + 8) = v1;
            }
            __syncthreads();
        } else {
            if (wn == pass * 64) {
#pragma unroll
                for (int i = 0; i < 4; ++i)
#pragma unroll
                    for (int j = 0; j < 4; ++j) {
                        bf16x4 pk = {(bf16_t)acc[i][j][0], (bf16_t)acc[i][j][1],
                                     (bf16_t)acc[i][j][2], (bf16_t)acc[i][j][3]};
                        *(bf16x4*)&Cs[(j * 16 + lr) * 136 + wm + i * 16 + hi * 4] = pk;
                    }
            }
            __syncthreads();
#pragma unroll
            for (int it = 0; it < 2; ++it) {
                const int lrow = it * 32 + (tid >> 3);
                const int m0 = (tid & 7) * 16;
                bf16x8 v0 = *(const bf16x8*)&Cs[lrow * 136 + m0];
                bf16x8 v1 = *(const bf16x8*)&Cs[lrow * 136 + m0 + 8];
                const int n = nt * 128 + pass * 64 + lrow;
                bf16_t* dst = g.O + (size_t)b * g.Ob + (size_t)c * g.Oc +
                              (size_t)(n >> 5) * g.Onh + (size_t)(n & 31) * g.Onp + m0;
                *(bf16x8*)dst = v0;
                *(bf16x8*)(dst + 8) = v1;
            }
            __syncthreads();
        }
    }
}

// ---------------------------------------------------------------------------
// Fused epilogue mega-kernel:
//   S = A1*Wos ; T = A2*Wot ; AO = LN(x+S)+LN(x+T)
//   h = relu(AO*W1+b1) ; F = h*W2+b2 ; out = LN(AO+F)      (f32 out)
// Block = 64 rows x 256 cols, 4 waves = n-slices. AO lives in registers
// (row-thread layout) + one LDS tile for the W1-loop A-operand. x read once
// from the ORIGINAL f32 input (kept in bf16 regs across the T-loop) -> the
// kernel never reads d_out, so the f32 out-write is race-free.
// LDS phases (elems): stage 2x10240 [0,20480) ; Ss/Ts [20480,37376) ;
// AO-tile/Hs [0,16896) ; W-stage 2x8192 [20480,36864) ; Fs [20480,37376).
// Peak 37376 elems = 74.75 KB -> 2 blocks/CU. K-loops: depth-1 counted vmcnt
// (R5's best-measured schedule for this geometry).
// ---------------------------------------------------------------------------
__global__ __launch_bounds__(256) void epilogue_fused(
    const bf16_t* __restrict__ A1, const bf16_t* __restrict__ A2,
    const bf16_t* __restrict__ Wos, const bf16_t* __restrict__ Wot,
    const bf16_t* __restrict__ Wf1, const bf16_t* __restrict__ Wf2,
    const float* __restrict__ xf, const float* __restrict__ b1v,
    const float* __restrict__ b2v, const float* __restrict__ g,
    const float* __restrict__ beta, float* __restrict__ out)
{
    const int bx = blockIdx.x, c = blockIdx.z;
    const int R = ((bx >> 1) * Cn + c) * Sn + (bx & 1) * 64;

    __shared__ bf16_t lds[37376];

    const int tid = threadIdx.x, wv = tid >> 6, ln = tid & 63;
    const int wn = wv * 64, lr = ln & 15, hi = ln >> 4;
    const int row = tid >> 2, c0 = (tid & 3) * 64;

    const bf16_t* WosB = Wos + (size_t)c * 65536;
    const bf16_t* WotB = Wot + (size_t)c * 65536;
    const bf16_t* W1b  = Wf1 + (size_t)c * 65536;
    const bf16_t* W2b  = Wf2 + (size_t)c * 65536;

    // stage A(64x32)+W(128x32) -> stage buf [buf*10240, +10240)  (5 insts/wave)
    auto stageAW = [&](int buf, int kt, const bf16_t* Asrc, const bf16_t* Wsrc) {
        const int k0 = kt * 32;
        bf16_t* base = &lds[buf * 10240];
        {
            const int ch = wv * 64 + ln;
            const int r2 = ch >> 2;
            const int kc = (((ch & 3) ^ ((r2 >> 1) & 3)) * 8);
            gl2lds16(Asrc + (size_t)r2 * 256 + k0 + kc, base + ch * 8);
        }
#pragma unroll
        for (int g2 = 0; g2 < 4; ++g2) {
            const int ch = g2 * 256 + wv * 64 + ln;
            const int r2 = ch >> 2;
            const int kc = (((ch & 3) ^ ((r2 >> 1) & 3)) * 8);
            gl2lds16(Wsrc + (size_t)r2 * 256 + k0 + kc, base + 2048 + ch * 8);
        }
    };
    // stage W-only (128x32) -> [20480 + buf*8192, +8192)  (4 insts/wave)
    auto stageW = [&](int buf, int kt, const bf16_t* Wsrc) {
        const int k0 = kt * 32;
#pragma unroll
        for (int g2 = 0; g2 < 4; ++g2) {
            const int ch = g2 * 256 + wv * 64 + ln;
            const int r2 = ch >> 2;
            const int kc = (((ch & 3) ^ ((r2 >> 1) & 3)) * 8);
            gl2lds16(Wsrc + (size_t)r2 * 256 + k0 + kc,
                     &lds[20480 + buf * 8192] + ch * 8);
        }
    };

    f32x4 acc[4][4];
    bf16x8 ao_r[8], xv_r[8];
    bf16_t* STs = &lds[20480];          // Ss/Ts slot (also Fs later)

    // =================== S branch: acc = A1 * Wos ===================
    {
        const bf16_t* Ab = A1 + (size_t)R * 256;
#pragma unroll
        for (int i = 0; i < 4; ++i)
#pragma unroll
            for (int j = 0; j < 4; ++j) acc[i][j] = (f32x4){0.f, 0.f, 0.f, 0.f};
        stageAW(0, 0, Ab, WosB);
#pragma unroll
        for (int t = 0; t < 8; ++t) {
            if (t < 7) {
                stageAW((t + 1) & 1, t + 1, Ab, WosB);
                asm volatile("s_waitcnt vmcnt(5)" ::: "memory");
            } else asm volatile("s_waitcnt vmcnt(0)" ::: "memory");
            __builtin_amdgcn_s_barrier();
            __builtin_amdgcn_sched_barrier(0);
            const bf16_t* base = &lds[(t & 1) * 10240];
            bf16x8 af[4], bfr[4];
#pragma unroll
            for (int i = 0; i < 4; ++i) {
                const int r = i * 16 + lr;
                af[i] = *(const bf16x8*)(base + r * 32 + ((hi ^ ((r >> 1) & 3)) * 8));
            }
#pragma unroll
            for (int j = 0; j < 4; ++j) {
                const int r = wn + j * 16 + lr;
                bfr[j] = *(const bf16x8*)(base + 2048 + r * 32 + ((hi ^ ((r >> 1) & 3)) * 8));
            }
            __builtin_amdgcn_s_setprio(1);
#pragma unroll
            for (int i = 0; i < 4; ++i)
#pragma unroll
                for (int j = 0; j < 4; ++j)
                    acc[i][j] = __builtin_amdgcn_mfma_f32_16x16x32_bf16(af[i], bfr[j], acc[i][j], 0, 0, 0);
            __builtin_amdgcn_s_setprio(0);
            __builtin_amdgcn_sched_barrier(0);
            __builtin_amdgcn_s_barrier();
        }
    }
    // stage Ss
#pragma unroll
    for (int i = 0; i < 4; ++i)
#pragma unroll
        for (int j = 0; j < 4; ++j)
#pragma unroll
            for (int r = 0; r < 4; ++r)
                STs[(i * 16 + hi * 4 + r) * 264 + wn + j * 16 + lr] = (bf16_t)acc[i][j][r];
    __syncthreads();

    // T-branch prologue overlaps LN1 (writes [0,20480); LN1 touches Ss+global)
    const bf16_t* Ab2 = A2 + (size_t)R * 256;
    stageAW(0, 0, Ab2, WotB);

    // ---------------- LN1: ao1 = LN(x + S) (regs) ----------------
    {
        const float* xp = xf + (size_t)(R + row) * 256 + c0;
        float s1 = 0, q1 = 0;
#pragma unroll
        for (int u = 0; u < 8; ++u) {
            const float4 xa = *(const float4*)(xp + u * 8);
            const float4 xb4 = *(const float4*)(xp + u * 8 + 4);
            bf16x8 xv;
            xv[0] = (bf16_t)xa.x; xv[1] = (bf16_t)xa.y; xv[2] = (bf16_t)xa.z; xv[3] = (bf16_t)xa.w;
            xv[4] = (bf16_t)xb4.x; xv[5] = (bf16_t)xb4.y; xv[6] = (bf16_t)xb4.z; xv[7] = (bf16_t)xb4.w;
            xv_r[u] = xv;
            bf16x8 sv = *(const bf16x8*)&STs[row * 264 + c0 + u * 8];
#pragma unroll
            for (int e = 0; e < 8; ++e) {
                const float a = (float)xv[e] + (float)sv[e];
                s1 += a; q1 += a * a;
            }
        }
        s1 += __shfl_xor(s1, 1); s1 += __shfl_xor(s1, 2);
        q1 += __shfl_xor(q1, 1); q1 += __shfl_xor(q1, 2);
        const float mu1 = s1 / 256.f;
        const float r1 = rsqrtf(q1 / 256.f - mu1 * mu1 + 1e-6f);
#pragma unroll
        for (int u = 0; u < 8; ++u) {
            bf16x8 sv = *(const bf16x8*)&STs[row * 264 + c0 + u * 8];
            bf16x8 o8;
#pragma unroll
            for (int e = 0; e < 8; ++e) {
                const int n = c0 + u * 8 + e;
                const float a = (float)xv_r[u][e] + (float)sv[e];
                o8[e] = (bf16_t)((a - mu1) * r1 * g[n] + beta[n]);
            }
            ao_r[u] = o8;
        }
    }

    // =================== T branch: acc = A2 * Wot ===================
    {
#pragma unroll
        for (int i = 0; i < 4; ++i)
#pragma unroll
            for (int j = 0; j < 4; ++j) acc[i][j] = (f32x4){0.f, 0.f, 0.f, 0.f};
#pragma unroll
        for (int t = 0; t < 8; ++t) {
            if (t < 7) {
                stageAW((t + 1) & 1, t + 1, Ab2, WotB);
                asm volatile("s_waitcnt vmcnt(5)" ::: "memory");
            } else asm volatile("s_waitcnt vmcnt(0)" ::: "memory");
            __builtin_amdgcn_s_barrier();
            __builtin_amdgcn_sched_barrier(0);
            const bf16_t* base = &lds[(t & 1) * 10240];
            bf16x8 af[4], bfr[4];
#pragma unroll
            for (int i = 0; i < 4; ++i) {
                const int r = i * 16 + lr;
                af[i] = *(const bf16x8*)(base + r * 32 + ((hi ^ ((r >> 1) & 3)) * 8));
            }
#pragma unroll
            for (int j = 0; j < 4; ++j) {
                const int r = wn + j * 16 + lr;
                bfr[j] = *(const bf16x8*)(base + 2048 + r * 32 + ((hi ^ ((r >> 1) & 3)) * 8));
            }
            __builtin_amdgcn_s_setprio(1);
#pragma unroll
            for (int i = 0; i < 4; ++i)
#pragma unroll
                for (int j = 0; j < 4; ++j)
                    acc[i][j] = __builtin_amdgcn_mfma_f32_16x16x32_bf16(af[i], bfr[j], acc[i][j], 0, 0, 0);
            __builtin_amdgcn_s_setprio(0);
            __builtin_amdgcn_sched_barrier(0);
            __builtin_amdgcn_s_barrier();
        }
    }
    // stage Ts (Ss dead after LN1; all waves past T-loop barriers)
#pragma unroll
    for (int i = 0; i < 4; ++i)
#pragma unroll
        for (int j = 0; j < 4; ++j)
#pragma unroll
            for (int r = 0; r < 4; ++r)
                STs[(i * 16 + hi * 4 + r) * 264 + wn + j * 16 + lr] = (bf16_t)acc[i][j][r];
    __syncthreads();

    // ---------------- LN2: ao = ao1 + LN(x + T); write AO-tile ----------------
    {
        float s2 = 0, q2 = 0;
#pragma unroll
        for (int u = 0; u < 8; ++u) {
            bf16x8 tv = *(const bf16x8*)&STs[row * 264 + c0 + u * 8];
#pragma unroll
            for (int e = 0; e < 8; ++e) {
                const float a = (float)xv_r[u][e] + (float)tv[e];
                s2 += a; q2 += a * a;
            }
        }
        s2 += __shfl_xor(s2, 1); s2 += __shfl_xor(s2, 2);
        q2 += __shfl_xor(q2, 1); q2 += __shfl_xor(q2, 2);
        const float mu2 = s2 / 256.f;
        const float r2 = rsqrtf(q2 / 256.f - mu2 * mu2 + 1e-6f);
#pragma unroll
        for (int u = 0; u < 8; ++u) {
            bf16x8 tv = *(const bf16x8*)&STs[row * 264 + c0 + u * 8];
            bf16x8 o8;
#pragma unroll
            for (int e = 0; e < 8; ++e) {
                const int n = c0 + u * 8 + e;
                const float a = (float)xv_r[u][e] + (float)tv[e];
                o8[e] = (bf16_t)((float)ao_r[u][e] + (a - mu2) * r2 * g[n] + beta[n]);
            }
            ao_r[u] = o8;
            *(bf16x8*)&lds[row * 264 + c0 + u * 8] = o8;   // AO-tile at [0,16896)
        }
    }
    __syncthreads();

    // =================== W1: h = relu(AO*W1 + b1) ===================
    {
#pragma unroll
        for (int i = 0; i < 4; ++i)
#pragma unroll
            for (int j = 0; j < 4; ++j) acc[i][j] = (f32x4){0.f, 0.f, 0.f, 0.f};
        stageW(0, 0, W1b);
#pragma unroll
        for (int t = 0; t < 8; ++t) {
            if (t < 7) {
                stageW((t + 1) & 1, t + 1, W1b);
                asm volatile("s_waitcnt vmcnt(4)" ::: "memory");
            } else asm volatile("s_waitcnt vmcnt(0)" ::: "memory");
            __builtin_amdgcn_s_barrier();
            __builtin_amdgcn_sched_barrier(0);
            bf16x8 af[4], bfr[4];
#pragma unroll
            for (int i = 0; i < 4; ++i)
                af[i] = *(const bf16x8*)&lds[(i * 16 + lr) * 264 + t * 32 + hi * 8];
#pragma unroll
            for (int j = 0; j < 4; ++j) {
                const int r = wn + j * 16 + lr;
                bfr[j] = *(const bf16x8*)(&lds[20480 + (t & 1) * 8192] + r * 32 +
                                          ((hi ^ ((r >> 1) & 3)) * 8));
            }
            __builtin_amdgcn_s_setprio(1);
#pragma unroll
            for (int i = 0; i < 4; ++i)
#pragma unroll
                for (int j = 0; j < 4; ++j)
                    acc[i][j] = __builtin_amdgcn_mfma_f32_16x16x32_bf16(af[i], bfr[j], acc[i][j], 0, 0, 0);
            __builtin_amdgcn_s_setprio(0);
            __builtin_amdgcn_sched_barrier(0);
            __builtin_amdgcn_s_barrier();
        }
    }
    // interlude: issue first W2 tile, write Hs (overwrites AO-tile), sync
    stageW(0, 0, W2b);
#pragma unroll
    for (int i = 0; i < 4; ++i)
#pragma unroll
        for (int j = 0; j < 4; ++j) {
            const int n = wn + j * 16 + lr;
            const float bv = b1v[c * 256 + n];
#pragma unroll
            for (int r = 0; r < 4; ++r)
                lds[(i * 16 + hi * 4 + r) * 264 + n] =
                    (bf16_t)fmaxf(acc[i][j][r] + bv, 0.f);
        }
    __syncthreads();

    // =================== W2: F = h*W2 + b2 ===================
    {
#pragma unroll
        for (int i = 0; i < 4; ++i)
#pragma unroll
            for (int j = 0; j < 4; ++j) acc[i][j] = (f32x4){0.f, 0.f, 0.f, 0.f};
#pragma unroll
        for (int t = 0; t < 8; ++t) {
            if (t < 7) {
                stageW((t + 1) & 1, t + 1, W2b);
                asm volatile("s_waitcnt vmcnt(4)" ::: "memory");
            } else asm volatile("s_waitcnt vmcnt(0)" ::: "memory");
            __builtin_amdgcn_s_barrier();
            __builtin_amdgcn_sched_barrier(0);
            bf16x8 af[4], bfr[4];
#pragma unroll
            for (int i = 0; i < 4; ++i)
                af[i] = *(const bf16x8*)&lds[(i * 16 + lr) * 264 + t * 32 + hi * 8];
#pragma unroll
            for (int j = 0; j < 4; ++j) {
                const int r = wn + j * 16 + lr;
                bfr[j] = *(const bf16x8*)(&lds[20480 + (t & 1) * 8192] + r * 32 +
                                          ((hi ^ ((r >> 1) & 3)) * 8));
            }
            __builtin_amdgcn_s_setprio(1);
#pragma unroll
            for (int i = 0; i < 4; ++i)
#pragma unroll
                for (int j = 0; j < 4; ++j)
                    acc[i][j] = __builtin_amdgcn_mfma_f32_16x16x32_bf16(af[i], bfr[j], acc[i][j], 0, 0, 0);
            __builtin_amdgcn_s_setprio(0);
            __builtin_amdgcn_sched_barrier(0);
            __builtin_amdgcn_s_barrier();
        }
    }
    // stage Fs (+b2) into STs area (W-stage dead after final barrier)
#pragma unroll
    for (int i = 0; i < 4; ++i)
#pragma unroll
        for (int j = 0; j < 4; ++j) {
            const int n = wn + j * 16 + lr;
            const float bv = b2v[c * 256 + n];
#pragma unroll
            for (int r = 0; r < 4; ++r)
                STs[(i * 16 + hi * 4 + r) * 264 + n] = (bf16_t)(acc[i][j][r] + bv);
        }
    __syncthreads();

    // ---------------- final LN(AO + F) -> f32 out ----------------
    {
        float s = 0, q = 0;
#pragma unroll
        for (int u = 0; u < 8; ++u) {
            bf16x8 fv = *(const bf16x8*)&STs[row * 264 + c0 + u * 8];
#pragma unroll
            for (int e = 0; e < 8; ++e) {
                const float a = (float)ao_r[u][e] + (float)fv[e];
                s += a; q += a * a;
            }
        }
        s += __shfl_xor(s, 1); s += __shfl_xor(s, 2);
        q += __shfl_xor(q, 1); q += __shfl_xor(q, 2);
        const float mu = s / 256.f;
        const float rin = rsqrtf(q / 256.f - mu * mu + 1e-6f);
#pragma unroll
        for (int u = 0; u < 8; ++u) {
            bf16x8 fv = *(const bf16x8*)&STs[row * 264 + c0 + u * 8];
            float4 o0, o1;
#pragma unroll
            for (int e = 0; e < 8; ++e) {
                const int n = c0 + u * 8 + e;
                const float a = (float)ao_r[u][e] + (float)fv[e];
                const float v = (a - mu) * rin * g[n] + beta[n];
                if (e < 4) (&o0.x)[e] = v; else (&o1.x)[e - 4] = v;
            }
            float* dst = out + (size_t)(R + row) * 256 + c0 + u * 8;
            *(float4*)dst = o0;
            *(float4*)(dst + 4) = o1;
        }
    }
}

// ---------------------------------------------------------------------------
// Spatial attention, MFMA, one wave per (b,s,h). 24x24 padded to 32.
// ---------------------------------------------------------------------------
__global__ __launch_bounds__(256) void attn_spatial_mfma(
    const bf16_t* __restrict__ Q, const bf16_t* __restrict__ K,
    const bf16_t* __restrict__ V, bf16_t* __restrict__ O)
{
    __shared__ bf16_t Ps[4][32 * 40];
    __shared__ bf16_t Vt[4][32 * 40];

    const int tid = threadIdx.x, wv = tid >> 6, ln = tid & 63;
    const int lr = ln & 15, hi = ln >> 4, lk = hi * 8;

    const int bsh = blockIdx.x * 4 + wv;
    const int h = bsh & 7, s = (bsh >> 3) & 127, b = bsh >> 10;
    const size_t qb = (size_t)bsh * (Cn * Pn);

    {
        const int p = ln >> 1, c0 = 24 + (ln & 1) * 4;
        bf16x4 z = {};
        *(bf16x4*)&Vt[wv][p * 40 + c0] = z;
    }
#pragma unroll
    for (int it = 0; it < 2; ++it) {
        const int ch = it * 64 + ln;
        if (ch < 96) {
            const int cc = ch >> 2, p0 = (ch & 3) * 8;
            bf16x8 v = *(const bf16x8*)(V + qb + cc * 32 + p0);
#pragma unroll
            for (int j = 0; j < 8; ++j)
                Vt[wv][(p0 + j) * 40 + cc] = v[j];
        }
    }

    bf16x8 aq0 = *(const bf16x8*)(Q + qb + lr * 32 + lk);
    bf16x8 aq1 = *(const bf16x8*)(Q + qb + (16 + lr) * 32 + lk);
    bf16x8 bk0 = *(const bf16x8*)(K + qb + lr * 32 + lk);
    bf16x8 bk1 = *(const bf16x8*)(K + qb + (16 + lr) * 32 + lk);
    const f32x4 zz = {0.f, 0.f, 0.f, 0.f};
    f32x4 sc[2][2];
    sc[0][0] = __builtin_amdgcn_mfma_f32_16x16x32_bf16(aq0, bk0, zz, 0, 0, 0);
    sc[0][1] = __builtin_amdgcn_mfma_f32_16x16x32_bf16(aq0, bk1, zz, 0, 0, 0);
    sc[1][0] = __builtin_amdgcn_mfma_f32_16x16x32_bf16(aq1, bk0, zz, 0, 0, 0);
    sc[1][1] = __builtin_amdgcn_mfma_f32_16x16x32_bf16(aq1, bk1, zz, 0, 0, 0);

    const float scale = 0.17677669529663687f;
#pragma unroll
    for (int i = 0; i < 2; ++i) {
        float s0[4], s1[4], mx[4];
#pragma unroll
        for (int r = 0; r < 4; ++r) {
            s0[r] = sc[i][0][r] * scale;
            s1[r] = (lr >= 8) ? -3.0e38f : sc[i][1][r] * scale;
            mx[r] = fmaxf(s0[r], s1[r]);
        }
#pragma unroll
        for (int d = 1; d < 16; d <<= 1)
#pragma unroll
            for (int r = 0; r < 4; ++r) mx[r] = fmaxf(mx[r], __shfl_xor(mx[r], d));
        float e0[4], e1[4], sm[4];
#pragma unroll
        for (int r = 0; r < 4; ++r) {
            e0[r] = __expf(s0[r] - mx[r]);
            e1[r] = __expf(s1[r] - mx[r]);
            sm[r] = e0[r] + e1[r];
        }
#pragma unroll
        for (int d = 1; d < 16; d <<= 1)
#pragma unroll
            for (int r = 0; r < 4; ++r) sm[r] += __shfl_xor(sm[r], d);
#pragma unroll
        for (int r = 0; r < 4; ++r) {
            const float inv = 1.f / sm[r];
            const int row = i * 16 + hi * 4 + r;
            Ps[wv][row * 40 + lr]      = (bf16_t)(e0[r] * inv);
            Ps[wv][row * 40 + 16 + lr] = (bf16_t)(e1[r] * inv);
        }
    }

    bf16x8 ap0 = *(const bf16x8*)&Ps[wv][lr * 40 + lk];
    bf16x8 ap1 = *(const bf16x8*)&Ps[wv][(16 + lr) * 40 + lk];
    bf16x8 bv0 = *(const bf16x8*)&Vt[wv][lr * 40 + lk];
    bf16x8 bv1 = *(const bf16x8*)&Vt[wv][(16 + lr) * 40 + lk];
    f32x4 o[2][2];
    o[0][0] = __builtin_amdgcn_mfma_f32_16x16x32_bf16(ap0, bv0, zz, 0, 0, 0);
    o[0][1] = __builtin_amdgcn_mfma_f32_16x16x32_bf16(ap0, bv1, zz, 0, 0, 0);
    o[1][0] = __builtin_amdgcn_mfma_f32_16x16x32_bf16(ap1, bv0, zz, 0, 0, 0);
    o[1][1] = __builtin_amdgcn_mfma_f32_16x16x32_bf16(ap1, bv1, zz, 0, 0, 0);

#pragma unroll
    for (int i = 0; i < 2; ++i)
#pragma unroll
        for (int r = 0; r < 4; ++r) {
            const int c = i * 16 + hi * 4 + r;
            if (c < 24) {
                const size_t ob = ((size_t)(b * Cn + c) * Sn + s) * En + h * Pn;
#pragma unroll
                for (int j = 0; j < 2; ++j)
                    O[ob + j * 16 + lr] = (bf16_t)o[i][j][r];
            }
        }
}

// ---------------------------------------------------------------------------
// Temporal attention, MFMA. One block (4 waves) per (b,h,c).
// ---------------------------------------------------------------------------
__global__ __launch_bounds__(256) void attn_temporal_mfma(
    const bf16_t* __restrict__ Q, const bf16_t* __restrict__ K,
    const bf16_t* __restrict__ Vt, bf16_t* __restrict__ O)
{
    const int c = blockIdx.x, h = blockIdx.y, b = blockIdx.z;
    const size_t base = ((size_t)(b * Hn + h) * Cn + c) * (Sn * Pn);

    __shared__ bf16_t Qs[128 * 32];
    __shared__ bf16_t Ks[128 * 32];
    __shared__ bf16_t Vs[32 * 136];
    __shared__ bf16_t Ps[128 * 136];

    const int tid = threadIdx.x, wv = tid >> 6, ln = tid & 63;
    const int lr = ln & 15, lk = (ln >> 4) * 8;

#pragma unroll
    for (int it = 0; it < 2; ++it) {
        const int cb = it * 256 + wv * 64;
        const int mc = cb + ln;
        const int row = mc >> 2, kc = (mc & 3) * 8;
        gl2lds16(Q + base + row * 32 + kc, &Qs[cb * 8]);
        gl2lds16(K + base + row * 32 + kc, &Ks[cb * 8]);
    }
#pragma unroll
    for (int it = 0; it < 2; ++it) {
        const int mc = it * 256 + tid;
        const int p = mc >> 4, scn = (mc & 15) * 8;
        bf16x8 v = *(const bf16x8*)(Vt + base + p * 128 + scn);
        *(bf16x8*)&Vs[p * 136 + scn] = v;
    }
    __syncthreads();

    const int r0 = wv * 32;
    bf16x8 aq0 = *(const bf16x8*)&Qs[(r0 + lr) * 32 + lk];
    bf16x8 aq1 = *(const bf16x8*)&Qs[(r0 + 16 + lr) * 32 + lk];
    f32x4 sc_[2][8];
    const f32x4 zz = {0.f, 0.f, 0.f, 0.f};
#pragma unroll
    for (int j = 0; j < 8; ++j) {
        bf16x8 bk = *(const bf16x8*)&Ks[(j * 16 + lr) * 32 + lk];
        sc_[0][j] = __builtin_amdgcn_mfma_f32_16x16x32_bf16(aq0, bk, zz, 0, 0, 0);
        sc_[1][j] = __builtin_amdgcn_mfma_f32_16x16x32_bf16(aq1, bk, zz, 0, 0, 0);
    }

    const float scale = 0.17677669529663687f;
#pragma unroll
    for (int i = 0; i < 2; ++i) {
        float mx[4], sm[4];
#pragma unroll
        for (int r = 0; r < 4; ++r) {
            float m = sc_[i][0][r];
#pragma unroll
            for (int j = 1; j < 8; ++j) m = fmaxf(m, sc_[i][j][r]);
            mx[r] = m;
        }
#pragma unroll
        for (int d = 1; d < 16; d <<= 1)
#pragma unroll
            for (int r = 0; r < 4; ++r) mx[r] = fmaxf(mx[r], __shfl_xor(mx[r], d));
#pragma unroll
        for (int r = 0; r < 4; ++r) sm[r] = 0.f;
#pragma unroll
        for (int j = 0; j < 8; ++j)
#pragma unroll
            for (int r = 0; r < 4; ++r) {
                const float e = __expf((sc_[i][j][r] - mx[r]) * scale);
                sc_[i][j][r] = e; sm[r] += e;
            }
#pragma unroll
        for (int d = 1; d < 16; d <<= 1)
#pragma unroll
            for (int r = 0; r < 4; ++r) sm[r] += __shfl_xor(sm[r], d);
        float inv[4];
#pragma unroll
        for (int r = 0; r < 4; ++r) inv[r] = 1.f / sm[r];
        const int rb = r0 + i * 16 + (ln >> 4) * 4;
#pragma unroll
        for (int j = 0; j < 8; ++j)
#pragma unroll
            for (int r = 0; r < 4; ++r)
                Ps[(rb + r) * 136 + j * 16 + lr] = (bf16_t)(sc_[i][j][r] * inv[r]);
    }
    __syncthreads();

    f32x4 o[2][2] = {};
#pragma unroll
    for (int kk = 0; kk < 4; ++kk) {
        bf16x8 ap0 = *(const bf16x8*)&Ps[(r0 + lr) * 136 + kk * 32 + lk];
        bf16x8 ap1 = *(const bf16x8*)&Ps[(r0 + 16 + lr) * 136 + kk * 32 + lk];
        bf16x8 bv0 = *(const bf16x8*)&Vs[lr * 136 + kk * 32 + lk];
        bf16x8 bv1 = *(const bf16x8*)&Vs[(16 + lr) * 136 + kk * 32 + lk];
        o[0][0] = __builtin_amdgcn_mfma_f32_16x16x32_bf16(ap0, bv0, o[0][0], 0, 0, 0);
        o[0][1] = __builtin_amdgcn_mfma_f32_16x16x32_bf16(ap0, bv1, o[0][1], 0, 0, 0);
        o[1][0] = __builtin_amdgcn_mfma_f32_16x16x32_bf16(ap1, bv0, o[1][0], 0, 0, 0);
        o[1][1] = __builtin_amdgcn_mfma_f32_16x16x32_bf16(ap1, bv1, o[1][1], 0, 0, 0);
    }

#pragma unroll
    for (int i = 0; i < 2; ++i) {
        const int sb = r0 + i * 16 + (ln >> 4) * 4;
#pragma unroll
        for (int j = 0; j < 2; ++j) {
            const int p = h * 32 + j * 16 + lr;
#pragma unroll
            for (int r = 0; r < 4; ++r)
                O[((size_t)(b * Cn + c) * Sn + (sb + r)) * En + p] = (bf16_t)o[i][j][r];
        }
    }
}

// ---------------------------------------------------------------------------
extern "C" void kernel_launch(void* const* d_in, const int* in_sizes, int n_in,
                              void* d_out, int out_size, void* d_ws, size_t ws_size,
                              hipStream_t stream)
{
    const float* x     = (const float*)d_in[0];
    const float* Wq_s  = (const float*)d_in[1];
    const float* Wk_s  = (const float*)d_in[2];
    const float* Wv_s  = (const float*)d_in[3];
    const float* Wo_s  = (const float*)d_in[4];
    const float* Wq_t  = (const float*)d_in[5];
    const float* Wk_t  = (const float*)d_in[6];
    const float* Wv_t  = (const float*)d_in[7];
    const float* Wo_t  = (const float*)d_in[8];
    const float* ln_g  = (const float*)d_in[9];
    const float* ln_b  = (const float*)d_in[10];
    const float* ff_w1 = (const float*)d_in[11];
    const float* ff_b1 = (const float*)d_in[12];
    const float* ff_w2 = (const float*)d_in[13];
    const float* ff_b2 = (const float*)d_in[14];
    float* out = (float*)d_out;

    bf16_t* wsb = (bf16_t*)d_ws;
    bf16_t* b0 = wsb;
    bf16_t* b1 = wsb + NBUF;
    bf16_t* b2 = wsb + 2 * NBUF;
    bf16_t* b3 = wsb + 3 * NBUF;
    bf16_t* b4 = wsb + 4 * NBUF;

    // d_out scratch: xb + {w_qs, w_qt, w_kt, w_vt} — all dead before the
    // f32 out write (epilogue_fused reads nothing from d_out).
    bf16_t* xb = (bf16_t*)d_out;
    bf16_t* wb = xb + NBUF;
    bf16_t* w_qs = wb + 0 * WSLOT;      // copy-convert slot
    bf16_t* wtr  = wb + 1 * WSLOT;      // 3 early transpose slots
    bf16_t* w_qt = wtr + 0 * WSLOT;
    bf16_t* w_kt = wtr + 1 * WSLOT;
    bf16_t* w_vt = wtr + 2 * WSLOT;
    bf16_t* w_ks = b4 + NBUF - 2 * 65536;   // consumed by spatial QKV before b4 written
    bf16_t* w_vs = b4 + NBUF - 65536;
    // late-converted weights (b0 free after attn_temporal reads its Q):
    bf16_t* w_os = b0;
    bf16_t* w_ot = b0 + WSLOT;
    bf16_t* w_f1 = b0 + 2 * WSLOT;
    bf16_t* w_f2 = b0 + 3 * WSLOT;

    // strides
    const int XAb = Cn * Sn * En, XAc = Sn * En, XAs = En;                          // [B,C,S,E]
    const int QSb = Sn * Hn * Cn * Pn, QSs = Hn * Cn * Pn, QSh = Cn * Pn;           // [B,S,H,C,P]
    const int QTb = Hn * Cn * Sn * Pn, QTh = Cn * Sn * Pn, QTc = Sn * Pn, QTs = Pn; // [B,H,C,S,P]
    const int WCP = 256 * 256;

    // --- conversions (source-major, coalesced) ---
    conv_x_k<<<NBUF / 1024, 256, 0, stream>>>(x, xb);
    conv_w_copy_k<<<1536, 256, 0, stream>>>(Wq_s, w_qs);
    conv_w_tr_k<<<dim3(32, 24, 3), 256, 0, stream>>>(
        TDesc{Wq_t, En * Pn, Cn * En * Pn, Pn},       // [h,c,e,p]: g=h
        TDesc{Wk_t, En * Pn, Cn * En * Pn, Pn},
        TDesc{Wv_t, En * Pn, Cn * En * Pn, Pn},
        TDesc{Wq_t, En * Pn, Cn * En * Pn, Pn},
        TDesc{Wq_t, En * Pn, Cn * En * Pn, Pn},
        wtr);
    conv_w_k2<<<dim3(256, 2), 256, 0, stream>>>(Wk_s, Wv_s, w_ks, w_vs);

    // --- spatial branch QKV + attention -> b3 ---
    gemm_mfma<3><<<dim3(16, 6, 24), 256, 0, stream>>>(
        xb, XAb, XAc, XAs,
        GDesc{w_qs, b0, 0, WCP, QSb, Pn, QSs, QSh, 1, 0},
        GDesc{w_ks, b1, 0, 0,   QSb, Pn, QSs, QSh, 1, 0},
        GDesc{w_vs, b2, 0, 0,   QSb, Pn, QSs, QSh, 1, 0});
    attn_spatial_mfma<<<Bn * Sn * Hn / 4, 256, 0, stream>>>(b0, b1, b2, b3);

    // --- temporal branch QKV + attention -> b4 ---
    gemm_mfma<3><<<dim3(16, 6, 24), 256, 0, stream>>>(
        xb, XAb, XAc, XAs,
        GDesc{w_qt, b0, 0, WCP, QTb, QTc, QTs, QTh, 1, 0},
        GDesc{w_kt, b1, 0, WCP, QTb, QTc, QTs, QTh, 1, 0},
        GDesc{w_vt, b2, 0, WCP, QTb, QTc, 1, QTh, Sn, 1});
    attn_temporal_mfma<<<dim3(24, 8, 16), 256, 0, stream>>>(b0, b1, b2, b4);

    // --- late conversion of epilogue weights into b0 (free after attn_t) ---
    conv_w_tr_k<<<dim3(32, 24, 4), 256, 0, stream>>>(
        TDesc{Wo_s, En * En, Pn, En},                 // [c,e,f]: g=f>>5
        TDesc{Wo_t, En * En, Pn, En},
        TDesc{ff_w1, En * En, Pn, En},
        TDesc{ff_w2, En * En, Pn, En},
        TDesc{Wo_s, En * En, Pn, En},
        b0);

    // --- single fused epilogue: Wo-proj x2 + dual LN + FF + final LN -> out ---
    epilogue_fused<<<dim3(32, 1, 24), 256, 0, stream>>>(
        b3, b4, w_os, w_ot, w_f1, w_f2, x, ff_b1, ff_b2, ln_g, ln_b, out);
}